// Round 14
// baseline (1006.827 us; speedup 1.0000x reference)
//
#include <hip/hip_runtime.h>
#include <stdint.h>

#define B_ 16
#define N_ 4096
#define D_ 64
#define S_ 1024
#define K_ 32
#define M_ (B_*S_*K_)   /* 524288 */
#define NQ_ (B_*S_)     /* 16384 */
#define EPS_ 1e-5f
#define WPAD 72         /* bf16 LDS row stride: 72*2=144 B, 16B-aligned frags */
#define FCH 64          /* fps chunk length (16 chunks -> ~40us visibility) */

typedef short bf16x8 __attribute__((ext_vector_type(8)));
typedef float f32x4  __attribute__((ext_vector_type(4)));
typedef float f32x2  __attribute__((ext_vector_type(2)));   // -> v_pk_* f32 ops

struct F3 { float x, y, z; };   // 12 B -> global_load_dwordx3, coalesced

static __device__ __forceinline__ float bf2f(uint16_t u){
  union{uint32_t i; float f;} v; v.i = ((uint32_t)u) << 16; return v.f;
}
static __device__ __forceinline__ uint16_t f2bf(float f){
  union{uint32_t i; float f;} v; v.f = f;
  uint32_t u = v.i;
  uint32_t r = (u + 0x7FFFu + ((u >> 16) & 1u)) >> 16;   // RNE, finite inputs
  return (uint16_t)r;
}

// One DPP max-combine step on a u64 key (verified bit-exact rounds 9-12).
#define DPP_MAXSTEP(k, CTRL) {                                                   \
  unsigned _lo = (unsigned)(k), _hi = (unsigned)((k) >> 32);                     \
  unsigned _plo = (unsigned)__builtin_amdgcn_update_dpp((int)_lo, (int)_lo,      \
                                                        CTRL, 0xf, 0xf, false); \
  unsigned _phi = (unsigned)__builtin_amdgcn_update_dpp((int)_hi, (int)_hi,      \
                                                        CTRL, 0xf, 0xf, false); \
  unsigned long long _pk = ((unsigned long long)_phi << 32) | _plo;              \
  if(_pk > (k)) (k) = _pk; }

// Build an MFMA A-fragment of h1 = relu(la0*y1 + lb0) in bf16 from the
// TRANSPOSED y1t layout (r19): u32 row c2 holds bf16 pair {2*c2, 2*c2+1} for
// all m (row stride M_). 4 dword loads; each 16-lane row-group reads 64 B
// contiguous. Same bits, same unpack order => bitwise-identical fragments.
static __device__ __forceinline__ bf16x8 h1_frag(const uint16_t* __restrict__ y1t,
                                                 const float* la0s, const float* lb0s,
                                                 int m, int kb){
  const uint32_t* __restrict__ y32 = (const uint32_t*)y1t;
  const int c2 = kb >> 1;
  uint32_t wrd[4];
#pragma unroll
  for(int i = 0; i < 4; ++i) wrd[i] = y32[(size_t)(c2 + i) * M_ + m];
  bf16x8 f;
#pragma unroll
  for(int i = 0; i < 4; ++i){
    int c0 = kb + 2*i;
    float v0 = bf2f((uint16_t)(wrd[i] & 0xFFFFu));
    float v1 = bf2f((uint16_t)(wrd[i] >> 16));
    float h0 = fmaxf(la0s[c0]   * v0 + lb0s[c0],   0.0f);
    float h1 = fmaxf(la0s[c0+1] * v1 + lb0s[c0+1], 0.0f);
    f[2*i]   = (short)f2bf(h0);
    f[2*i+1] = (short)f2bf(h1);
  }
  return f;
}

// ---------------------------------------------------------------------------
// 1) FPS: r12's verified 4-wave loop, split into 16 chunk dispatches of 64
//    iterations. DIAGNOSTIC round: per-extra-chunk overhead measured at
//    ~2.7us, so this costs ~+22us vs the 4-chunk 972.9 best — and drops the
//    rocprof visibility threshold to ~40us, exposing the never-measured
//    ~226us pool (ballq/layer2/layer3/final) by name. Re-merge next round.
//    Bit-exact state handoff via dstate/farws (r18-verified).
// ---------------------------------------------------------------------------
__global__ __launch_bounds__(256)
void fps_chunk_kernel(const float* __restrict__ xyz,
                      float* __restrict__ out_newxyz,
                      f32x2* __restrict__ dstate,
                      int* __restrict__ farws,
                      int it0, int itend, int is_first, int is_last){
  const int b = blockIdx.x;
  const int tid = threadIdx.x;
  const float* X = xyz + (size_t)b * N_ * 3;
  __shared__ float4 sxyz[N_];                       // 64 KB coord cache
  __shared__ __align__(16) unsigned long long slots[2][4];
  __shared__ float outbuf[FCH * 3];                 // 768 B chunk staging
  f32x2 px[8], py[8], pz[8], dist[8];
#pragma unroll
  for(int j = 0; j < 8; ++j){
    int p0 = tid + (2*j)   * 256;
    int p1 = tid + (2*j+1) * 256;
    px[j].x = X[p0*3 + 0]; px[j].y = X[p1*3 + 0];
    py[j].x = X[p0*3 + 1]; py[j].y = X[p1*3 + 1];
    pz[j].x = X[p0*3 + 2]; pz[j].y = X[p1*3 + 2];
    sxyz[p0] = make_float4(px[j].x, py[j].x, pz[j].x, 0.0f);
    sxyz[p1] = make_float4(px[j].y, py[j].y, pz[j].y, 0.0f);
  }
  if(is_first){
#pragma unroll
    for(int j = 0; j < 8; ++j){ dist[j].x = 1e10f; dist[j].y = 1e10f; }
  } else {
#pragma unroll
    for(int j = 0; j < 8; ++j) dist[j] = dstate[((size_t)b*8 + j)*256 + tid];
  }
  int far = is_first ? 0 : farws[b];                // reference: idx[0] = 0
  __syncthreads();
  for(int it = it0; it < itend; ++it){
    float4 c = sxyz[far];                           // broadcast b128 read
    if(tid == 0){                                   // LDS only
      int lo = (it - it0) * 3;
      outbuf[lo + 0] = c.x; outbuf[lo + 1] = c.y; outbuf[lo + 2] = c.z;
    }
    if(it == S_ - 1) break;                         // global last: no update
    f32x2 cx; cx.x = c.x; cx.y = c.x;
    f32x2 cy; cy.x = c.y; cy.y = c.y;
    f32x2 cz; cz.x = c.z; cz.y = c.z;
    float bestd = -1.0f; int bestt = 0;
#pragma unroll
    for(int j = 0; j < 8; ++j){
      f32x2 nd;
      {
#pragma clang fp contract(off)
        f32x2 dx = px[j] - cx, dy = py[j] - cy, dz = pz[j] - cz;
        f32x2 d  = dx*dx + dy*dy + dz*dz;   // ((dx2+dy2)+dz2), same assoc as scalar
        nd = __builtin_elementwise_min(dist[j], d);
      }
      dist[j] = nd;
      if(nd.x > bestd){ bestd = nd.x; bestt = 2*j; }      // t ascending ->
      if(nd.y > bestd){ bestd = nd.y; bestt = 2*j+1; }    // first max kept
    }
    const int bestp = tid + (bestt << 8);
    unsigned long long key = ((unsigned long long)__float_as_uint(bestd) << 32)
                           | (unsigned long long)(uint32_t)(~bestp);
    DPP_MAXSTEP(key, 0x111);
    DPP_MAXSTEP(key, 0x112);
    DPP_MAXSTEP(key, 0x114);
    DPP_MAXSTEP(key, 0x118);
    DPP_MAXSTEP(key, 0x142);
    DPP_MAXSTEP(key, 0x143);                        // lane 63 holds wave max
    const int par = it & 1;
    if((tid & 63) == 63) slots[par][tid >> 6] = key;
    __syncthreads();
    ulonglong2 s01 = *(const ulonglong2*)&slots[par][0];   // 2x ds_read_b128
    ulonglong2 s23 = *(const ulonglong2*)&slots[par][2];
    unsigned long long bk = s01.x;
    if(s01.y > bk) bk = s01.y;
    if(s23.x > bk) bk = s23.x;
    if(s23.y > bk) bk = s23.y;
    far = (int)(~(uint32_t)bk);                     // uniform across block
  }
  if(!is_last){                                     // hand off carried state
#pragma unroll
    for(int j = 0; j < 8; ++j) dstate[((size_t)b*8 + j)*256 + tid] = dist[j];
    if(tid == 0) farws[b] = far;
  }
  __syncthreads();
  float* O = out_newxyz + (size_t)b * S_ * 3 + (size_t)it0 * 3;
  const int cnt = (itend - it0) * 3;                // coalesced chunk drain
  for(int i = tid; i < cnt; i += 256) O[i] = outbuf[i];
}

// ---------------------------------------------------------------------------
// 2) Ball query, fp32 prefilter (r10-verified decisions) + dwordx3 coalesced
//    point loads; block 0 zeroes gstats (r12). Unchanged from r12.
// ---------------------------------------------------------------------------
__global__ __launch_bounds__(256) void ballq_kernel(const float* __restrict__ xyz,
                                                    const float* __restrict__ newxyz,
                                                    int* __restrict__ gidx,
                                                    float* __restrict__ gstats){
  const int tid = threadIdx.x;
  if(blockIdx.x == 0){                // fold: zero stats (512 floats)
    gstats[tid] = 0.0f; gstats[256 + tid] = 0.0f;
  }
  const int wslot = tid >> 6;
  const int lane  = tid & 63;
  const int q = blockIdx.x * 4 + wslot;
  const int b = q >> 10;
  const F3* XP = (const F3*)(xyz + (size_t)b * N_ * 3);
  const double R2D = 0.2 * 0.2;
  float nxf, nyf, nzf, saf;
  double nx, ny, nz, sa;
  {
    const float* NP = newxyz + (size_t)q * 3;
    nxf = NP[0]; nyf = NP[1]; nzf = NP[2];
    saf = nxf*nxf + nyf*nyf + nzf*nzf;
    nx = (double)nxf; ny = (double)nyf; nz = (double)nzf;
    sa = nx*nx + ny*ny + nz*nz;
  }
  __shared__ int sidx[4][K_];
  int count = 0;
  for(int base = 0; base < N_; base += 64){
    int p = base + lane;
    F3 pt = XP[p];                                  // global_load_dwordx3
    float sb32 = pt.x*pt.x + pt.y*pt.y + pt.z*pt.z;
    float dt32 = nxf*pt.x + nyf*pt.y + nzf*pt.z;
    float sq32 = saf + sb32 - 2.0f * dt32;
    bool band = fabsf(sq32 - 0.04f) < 5e-5f;
    bool inb;
    if(__ballot(band) != 0ull){
      double pxv = (double)pt.x, pyv = (double)pt.y, pzv = (double)pt.z;
      double sb = pxv*pxv + pyv*pyv + pzv*pzv;
      double dt = nx*pxv + ny*pyv + nz*pzv;
      double sq = sa + sb - 2.0 * dt;
      inb = !(sq > R2D);
    } else {
      inb = !(sq32 > 0.04f);
    }
    unsigned long long mask = __ballot(inb);
    int pos = count + __popcll(mask & ((1ull << lane) - 1ull));
    if(inb && pos < K_) sidx[wslot][pos] = p;
    count += (int)__popcll(mask);
    if(count >= K_) break;
  }
  __syncthreads();
  int nvalid = count < K_ ? count : K_;
  if(lane < K_){
    int first = sidx[wslot][0];
    int v = (lane < nvalid) ? sidx[wslot][lane] : first;
    gidx[(size_t)q * K_ + lane] = v;
  }
}

// ---------------------------------------------------------------------------
// 3) Layer 1 r21 (verified best: 972.9 total): LDS-tiled fp32 GEMM.
//    128m x 64o tile, 256 threads, 8m x 4o micro-tile -> acc[8][4] = 32
//    VGPRs statically indexed. xT[c][m] 34.3KB + wT[c][o] 17.2KB in LDS.
//    r23 (conflict split) and r24 (wT->global, 4 blocks/CU) both measured
//    neutral-to-worse => this exact variant is the best known.
// ---------------------------------------------------------------------------
__global__ __launch_bounds__(256)
void layer1_kernel(const float* __restrict__ xyz,
                   const float* __restrict__ pts,
                   const float* __restrict__ newxyz,
                   const int* __restrict__ gidx,
                   const float* __restrict__ w,
                   const float* __restrict__ bias,
                   uint16_t* __restrict__ y1t,
                   float* __restrict__ gstats){
  __shared__ float xT[67*128];                      // 34.3 KB  xT[c][m]
  __shared__ float wT[67*64];                       // 17.2 KB  wT[c][o]
  __shared__ float sm_sum[64], sm_sq[64];
  const int tid = threadIdx.x;
  const int bm = blockIdx.x * 128;

  for(int i = tid; i < 67*64; i += 256){            // w: coalesced read,
    int o = i / 67, c = i - o*67;                   // scattered LDS write
    wT[c*64 + o] = w[i];                            // (one-time)
  }
  {                                                 // gather + transpose x
    const int r = tid >> 1, h = tid & 1;            // 2 threads per row
    const int m = bm + r;
    const int bs = m >> 5, b = bs >> 10;
    const int j = gidx[m];
    const float4* pr = (const float4*)(pts + ((size_t)b * N_ + j) * D_);
    if(h == 0){
      const float* nxp = newxyz + (size_t)bs * 3;
      const float* pp  = xyz + ((size_t)b * N_ + j) * 3;
      xT[0*128 + r] = pp[0] - nxp[0];
      xT[1*128 + r] = pp[1] - nxp[1];
      xT[2*128 + r] = pp[2] - nxp[2];
#pragma unroll
      for(int k = 0; k < 8; ++k){
        float4 v = pr[k];
        xT[(3 + 4*k + 0)*128 + r] = v.x; xT[(3 + 4*k + 1)*128 + r] = v.y;
        xT[(3 + 4*k + 2)*128 + r] = v.z; xT[(3 + 4*k + 3)*128 + r] = v.w;
      }
    } else {
#pragma unroll
      for(int k = 8; k < 16; ++k){
        float4 v = pr[k];
        xT[(3 + 4*k + 0)*128 + r] = v.x; xT[(3 + 4*k + 1)*128 + r] = v.y;
        xT[(3 + 4*k + 2)*128 + r] = v.z; xT[(3 + 4*k + 3)*128 + r] = v.w;
      }
    }
  }
  __syncthreads();

  const int mq = tid & 15;                          // 8 m's: mq*8 .. +7
  const int oq = tid >> 4;                          // 4 o's: oq*4 .. +3
  float acc[8][4];
  {
    float4 bv = *(const float4*)&bias[oq*4];
#pragma unroll
    for(int mi = 0; mi < 8; ++mi){
      acc[mi][0] = bv.x; acc[mi][1] = bv.y; acc[mi][2] = bv.z; acc[mi][3] = bv.w;
    }
  }
  for(int c = 0; c < 67; ++c){
    f32x4 xa = *(const f32x4*)&xT[c*128 + mq*8];
    f32x4 xb = *(const f32x4*)&xT[c*128 + mq*8 + 4];
    f32x4 wv = *(const f32x4*)&wT[c*64 + oq*4];
#pragma unroll
    for(int mi = 0; mi < 4; ++mi){
      float xv = xa[mi];
#pragma unroll
      for(int oi = 0; oi < 4; ++oi) acc[mi][oi] = fmaf(wv[oi], xv, acc[mi][oi]);
    }
#pragma unroll
    for(int mi = 4; mi < 8; ++mi){
      float xv = xb[mi-4];
#pragma unroll
      for(int oi = 0; oi < 4; ++oi) acc[mi][oi] = fmaf(wv[oi], xv, acc[mi][oi]);
    }
  }

  // stats: fold mi, then shuffle-reduce across mq (lane low 4 bits)
  {
    float s[4], q[4];
#pragma unroll
    for(int oi = 0; oi < 4; ++oi){
      float ss = 0.f, qq = 0.f;
#pragma unroll
      for(int mi = 0; mi < 8; ++mi){
        ss += acc[mi][oi]; qq = fmaf(acc[mi][oi], acc[mi][oi], qq);
      }
      s[oi] = ss; q[oi] = qq;
    }
#pragma unroll
    for(int d = 1; d < 16; d <<= 1){
#pragma unroll
      for(int oi = 0; oi < 4; ++oi){
        s[oi] += __shfl_xor(s[oi], d, 64);
        q[oi] += __shfl_xor(q[oi], d, 64);
      }
    }
    if(mq == 0){
#pragma unroll
      for(int oi = 0; oi < 4; ++oi){
        sm_sum[oq*4 + oi] = s[oi];                  // unique writer per o
        sm_sq [oq*4 + oi] = q[oi];
      }
    }
  }

  // y1 store: transposed u32 pairs, 8 consecutive m -> 2x dwordx4 per o2
  {
    uint32_t* __restrict__ y1o = (uint32_t*)y1t;
#pragma unroll
    for(int p = 0; p < 2; ++p){
      uint32_t pk[8];
#pragma unroll
      for(int mi = 0; mi < 8; ++mi){
        uint32_t lo = (uint32_t)f2bf(acc[mi][2*p]);
        uint32_t hi = (uint32_t)f2bf(acc[mi][2*p + 1]);
        pk[mi] = lo | (hi << 16);
      }
      uint32_t* dst = &y1o[(size_t)(oq*2 + p) * M_ + bm + mq*8];
      *(uint4*)(dst)     = make_uint4(pk[0], pk[1], pk[2], pk[3]);
      *(uint4*)(dst + 4) = make_uint4(pk[4], pk[5], pk[6], pk[7]);
    }
  }
  __syncthreads();
  if(tid < 64)       atomicAdd(&gstats[tid],      sm_sum[tid]);
  else if(tid < 128) atomicAdd(&gstats[tid],      sm_sq[tid - 64]);
}

// ---------------------------------------------------------------------------
// 4) Layer 2 stats via MFMA, 512 m/block (r12). Same mfma order as layer3's
//    recompute => bitwise-identical z2. Reads transposed y1t via h1_frag.
// ---------------------------------------------------------------------------
__global__ __launch_bounds__(256)
void layer2_stats_kernel(const uint16_t* __restrict__ y1t,
                         const float* __restrict__ gstats0,
                         const float* __restrict__ g0,
                         const float* __restrict__ bt0,
                         const float* __restrict__ w1,
                         const float* __restrict__ b1,
                         float* __restrict__ gstats1){
  __shared__ short w1b[64*WPAD];
  __shared__ float la0s[64], lb0s[64], b1s[64];
  __shared__ float ssum[64], ssq[64];
  const int tid = threadIdx.x;
#pragma unroll
  for(int i = 0; i < 16; ++i){
    int e = i*256 + tid;
    w1b[(e>>6)*WPAD + (e&63)] = (short)f2bf(w1[e]);
  }
  if(tid < 64){
    float mean = gstats0[tid] * (1.0f / M_);
    float var  = gstats0[64 + tid] * (1.0f / M_) - mean * mean;
    float inv  = 1.0f / sqrtf(var + EPS_);
    float a = g0[tid] * inv;
    la0s[tid] = a; lb0s[tid] = bt0[tid] - mean * a;
    b1s[tid] = b1[tid];
  } else if(tid < 128){
    ssum[tid-64] = 0.f; ssq[tid-64] = 0.f;
  }
  __syncthreads();

  const int wave = tid >> 6, lane = tid & 63;
  const int row = lane & 15, quad = lane >> 4;

  for(int ck = 0; ck < 4; ++ck){
    const int wm0 = blockIdx.x * 512 + ck * 128 + wave * 32;
    bf16x8 afr[2][2];
#pragma unroll
    for(int s = 0; s < 2; ++s)
#pragma unroll
      for(int k2 = 0; k2 < 2; ++k2)
        afr[s][k2] = h1_frag(y1t, la0s, lb0s, wm0 + s*16 + row, quad*8 + k2*32);

    for(int ot = 0; ot < 4; ++ot){
      bf16x8 bfr0 = *(const bf16x8*)&w1b[(ot*16 + row)*WPAD + quad*8];
      bf16x8 bfr1 = *(const bf16x8*)&w1b[(ot*16 + row)*WPAD + quad*8 + 32];
      const float bb = b1s[ot*16 + row];
      float sum_ = 0.f, sq_ = 0.f;
#pragma unroll
      for(int s = 0; s < 2; ++s){
        f32x4 acc = {0.f, 0.f, 0.f, 0.f};
        acc = __builtin_amdgcn_mfma_f32_16x16x32_bf16(afr[s][0], bfr0, acc, 0, 0, 0);
        acc = __builtin_amdgcn_mfma_f32_16x16x32_bf16(afr[s][1], bfr1, acc, 0, 0, 0);
#pragma unroll
        for(int r = 0; r < 4; ++r){
          float z = acc[r] + bb;
          sum_ += z; sq_ = fmaf(z, z, sq_);
        }
      }
      sum_ += __shfl_xor(sum_, 16, 64); sum_ += __shfl_xor(sum_, 32, 64);
      sq_  += __shfl_xor(sq_,  16, 64); sq_  += __shfl_xor(sq_,  32, 64);
      if(quad == 0){
        atomicAdd(&ssum[ot*16 + row], sum_);
        atomicAdd(&ssq [ot*16 + row], sq_);
      }
    }
  }
  __syncthreads();
  if(tid < 64)       atomicAdd(&gstats1[tid], ssum[tid]);
  else if(tid < 128) atomicAdd(&gstats1[tid], ssq[tid - 64]);
}

// ---------------------------------------------------------------------------
// 5) Layer 3 via MFMA, 512 m/block (r12). h2 staging wave-private; same mfma
//    order as layer2_stats; fused stats2 + k-group max/min. Transposed y1t.
// ---------------------------------------------------------------------------
__global__ __launch_bounds__(256)
void layer3_kernel(const uint16_t* __restrict__ y1t,
                   const float* __restrict__ gstats0,
                   const float* __restrict__ g0,
                   const float* __restrict__ bt0,
                   const float* __restrict__ w1,
                   const float* __restrict__ b1,
                   const float* __restrict__ gstats1,
                   const float* __restrict__ g1,
                   const float* __restrict__ bt1,
                   const float* __restrict__ w2,
                   const float* __restrict__ b2,
                   float* __restrict__ gstats2,
                   float* __restrict__ maxk,
                   float* __restrict__ mink){
  __shared__ short w1b[64*WPAD];
  __shared__ short w2b[128*WPAD];
  __shared__ short h2s[4][32*WPAD];
  __shared__ float la0s[64], lb0s[64], la1s[64], lb1s[64], b1s[64], b2s[128];
  __shared__ float ssum[128], ssq[128];
  const int tid = threadIdx.x;
#pragma unroll
  for(int i = 0; i < 16; ++i){
    int e = i*256 + tid;
    w1b[(e>>6)*WPAD + (e&63)] = (short)f2bf(w1[e]);
  }
#pragma unroll
  for(int i = 0; i < 32; ++i){
    int e = i*256 + tid;
    w2b[(e>>6)*WPAD + (e&63)] = (short)f2bf(w2[e]);
  }
  if(tid < 64){
    float mean = gstats0[tid] * (1.0f / M_);
    float var  = gstats0[64 + tid] * (1.0f / M_) - mean * mean;
    float inv  = 1.0f / sqrtf(var + EPS_);
    float a = g0[tid] * inv;
    la0s[tid] = a; lb0s[tid] = bt0[tid] - mean * a;
    b1s[tid] = b1[tid];
  } else if(tid < 128){
    int o = tid - 64;
    float mean = gstats1[o] * (1.0f / M_);
    float var  = gstats1[64 + o] * (1.0f / M_) - mean * mean;
    float inv  = 1.0f / sqrtf(var + EPS_);
    float a = g1[o] * inv;
    la1s[o] = a; lb1s[o] = bt1[o] - mean * a;
  }
  if(tid < 128){ b2s[tid] = b2[tid]; ssum[tid] = 0.f; }
  else         { ssq[tid - 128] = 0.f; }
  __syncthreads();

  const int wave = tid >> 6, lane = tid & 63;
  const int row = lane & 15, quad = lane >> 4;
  short* h2w = &h2s[wave][0];

  for(int ck = 0; ck < 4; ++ck){
    const int wm0 = blockIdx.x * 512 + ck * 128 + wave * 32;
    {
      bf16x8 afr[2][2];
#pragma unroll
      for(int s = 0; s < 2; ++s)
#pragma unroll
        for(int k2 = 0; k2 < 2; ++k2)
          afr[s][k2] = h1_frag(y1t, la0s, lb0s, wm0 + s*16 + row, quad*8 + k2*32);

      for(int ot = 0; ot < 4; ++ot){
        bf16x8 bfr0 = *(const bf16x8*)&w1b[(ot*16 + row)*WPAD + quad*8];
        bf16x8 bfr1 = *(const bf16x8*)&w1b[(ot*16 + row)*WPAD + quad*8 + 32];
        const int o = ot*16 + row;
        const float bb = b1s[o], a1 = la1s[o], c1 = lb1s[o];
#pragma unroll
        for(int s = 0; s < 2; ++s){
          f32x4 acc = {0.f, 0.f, 0.f, 0.f};
          acc = __builtin_amdgcn_mfma_f32_16x16x32_bf16(afr[s][0], bfr0, acc, 0, 0, 0);
          acc = __builtin_amdgcn_mfma_f32_16x16x32_bf16(afr[s][1], bfr1, acc, 0, 0, 0);
#pragma unroll
          for(int r = 0; r < 4; ++r){
            float z = acc[r] + bb;
            float h = fmaxf(a1 * z + c1, 0.0f);
            int ml = s*16 + quad*4 + r;
            h2w[ml*WPAD + o] = (short)f2bf(h);
          }
        }
      }
    }
    {
      bf16x8 hfr[2][2];
#pragma unroll
      for(int s = 0; s < 2; ++s)
#pragma unroll
        for(int k2 = 0; k2 < 2; ++k2)
          hfr[s][k2] = *(const bf16x8*)&h2w[(s*16 + row)*WPAD + quad*8 + k2*32];

      for(int ot = 0; ot < 8; ++ot){
        bf16x8 bfr0 = *(const bf16x8*)&w2b[(ot*16 + row)*WPAD + quad*8];
        bf16x8 bfr1 = *(const bf16x8*)&w2b[(ot*16 + row)*WPAD + quad*8 + 32];
        const int o = ot*16 + row;
        const float bb = b2s[o];
        float sum_ = 0.f, sq_ = 0.f, mx = -1e30f, mn = 1e30f;
#pragma unroll
        for(int s = 0; s < 2; ++s){
          f32x4 acc = {0.f, 0.f, 0.f, 0.f};
          acc = __builtin_amdgcn_mfma_f32_16x16x32_bf16(hfr[s][0], bfr0, acc, 0, 0, 0);
          acc = __builtin_amdgcn_mfma_f32_16x16x32_bf16(hfr[s][1], bfr1, acc, 0, 0, 0);
#pragma unroll
          for(int r = 0; r < 4; ++r){
            float z = acc[r] + bb;
            sum_ += z; sq_ = fmaf(z, z, sq_);
            mx = fmaxf(mx, z); mn = fminf(mn, z);
          }
        }
        sum_ += __shfl_xor(sum_, 16, 64); sum_ += __shfl_xor(sum_, 32, 64);
        sq_  += __shfl_xor(sq_,  16, 64); sq_  += __shfl_xor(sq_,  32, 64);
        mx = fmaxf(mx, __shfl_xor(mx, 16, 64)); mx = fmaxf(mx, __shfl_xor(mx, 32, 64));
        mn = fminf(mn, __shfl_xor(mn, 16, 64)); mn = fminf(mn, __shfl_xor(mn, 32, 64));
        if(quad == 0){
          atomicAdd(&ssum[o], sum_);
          atomicAdd(&ssq [o], sq_);
          maxk[(size_t)(wm0 >> 5) * 128 + o] = mx;
          mink[(size_t)(wm0 >> 5) * 128 + o] = mn;
        }
      }
    }
  }
  __syncthreads();
  if(tid < 128) atomicAdd(&gstats2[tid], ssum[tid]);
  else          atomicAdd(&gstats2[tid], ssq[tid - 128]);
}

// ---------------------------------------------------------------------------
// 6) Final: BN2+ReLU on max/min endpoints. Unchanged.
// ---------------------------------------------------------------------------
__global__ __launch_bounds__(256) void final_kernel(const float* __restrict__ maxk,
                                                    const float* __restrict__ mink,
                                                    const float* __restrict__ gstats2,
                                                    const float* __restrict__ g,
                                                    const float* __restrict__ bt,
                                                    float* __restrict__ out_np){
  const int gid = blockIdx.x * 256 + threadIdx.x;
  const int o = gid & 127;
  float mean = gstats2[o] * (1.0f / M_);
  float var  = gstats2[128 + o] * (1.0f / M_) - mean * mean;
  float inv  = 1.0f / sqrtf(var + EPS_);
  float a = g[o] * inv;
  float b = bt[o] - mean * a;
  float mx = maxk[gid], mn = mink[gid];
  out_np[gid] = fmaxf(fmaxf(a * mx + b, 0.0f), fmaxf(a * mn + b, 0.0f));
}

// ---------------------------------------------------------------------------
extern "C" void kernel_launch(void* const* d_in, const int* in_sizes, int n_in,
                              void* d_out, int out_size, void* d_ws, size_t ws_size,
                              hipStream_t stream){
  (void)in_sizes; (void)n_in; (void)out_size;
  const float* xyz = (const float*)d_in[0];
  const float* pts = (const float*)d_in[1];
  const float* w0 = (const float*)d_in[2];  const float* b0  = (const float*)d_in[3];
  const float* g0 = (const float*)d_in[4];  const float* bt0 = (const float*)d_in[5];
  const float* w1 = (const float*)d_in[6];  const float* b1  = (const float*)d_in[7];
  const float* g1 = (const float*)d_in[8];  const float* bt1 = (const float*)d_in[9];
  const float* w2 = (const float*)d_in[10]; const float* b2  = (const float*)d_in[11];
  const float* g2 = (const float*)d_in[12]; const float* bt2 = (const float*)d_in[13];

  float* out    = (float*)d_out;
  float* newxyz = out;                       // (B,S,3)
  float* newpts = out + (size_t)B_ * S_ * 3; // (B,S,128)

  const size_t off_gidx  = 0;
  const size_t off_stats = off_gidx  + (size_t)M_ * 4;
  const size_t off_maxk  = off_stats + 65536;
  const size_t off_mink  = off_maxk  + (size_t)NQ_ * 128 * 4;
  const size_t off_y1    = off_mink  + (size_t)NQ_ * 128 * 4;
  const size_t off_fd    = off_y1    + (size_t)M_ * 64 * 2;   // fps dist state
  const size_t off_ff    = off_fd    + (size_t)B_ * 8 * 256 * 8; // fps far
  const size_t need      = off_ff    + 256;
  if(ws_size < need) return;

  char* ws = (char*)d_ws;
  int*      gidx   = (int*)     (ws + off_gidx);
  float*    gstats = (float*)   (ws + off_stats);
  float*    maxk   = (float*)   (ws + off_maxk);
  float*    mink   = (float*)   (ws + off_mink);
  uint16_t* y1t    = (uint16_t*)(ws + off_y1);
  f32x2*    dstate = (f32x2*)   (ws + off_fd);
  int*      farws  = (int*)     (ws + off_ff);

  for(int k = 0; k < 16; ++k){
    fps_chunk_kernel<<<B_, 256, 0, stream>>>(xyz, newxyz, dstate, farws,
                                             k*FCH, (k+1)*FCH,
                                             k == 0 ? 1 : 0, k == 15 ? 1 : 0);
  }
  ballq_kernel<<<NQ_ / 4, 256, 0, stream>>>(xyz, newxyz, gidx, gstats);

  layer1_kernel      <<<M_ / 128, 256, 0, stream>>>(xyz, pts, newxyz, gidx, w0, b0, y1t, gstats);
  layer2_stats_kernel<<<M_ / 512, 256, 0, stream>>>(y1t, gstats, g0, bt0, w1, b1, gstats + 128);
  layer3_kernel      <<<M_ / 512, 256, 0, stream>>>(y1t, gstats, g0, bt0, w1, b1,
                                                    gstats + 128, g1, bt1, w2, b2,
                                                    gstats + 256, maxk, mink);
  final_kernel<<<(NQ_ * 128) / 256, 256, 0, stream>>>(maxk, mink, gstats + 256, g2, bt2, newpts);
}

// Round 15
// 970.746 us; speedup vs baseline: 1.0372x; 1.0372x over previous
//
#include <hip/hip_runtime.h>
#include <stdint.h>

#define B_ 16
#define N_ 4096
#define D_ 64
#define S_ 1024
#define K_ 32
#define M_ (B_*S_*K_)   /* 524288 */
#define NQ_ (B_*S_)     /* 16384 */
#define EPS_ 1e-5f
#define WPAD 72         /* bf16 LDS row stride: 72*2=144 B, 16B-aligned frags */
#define FCH 256         /* fps chunk length: 4 chunks = measured optimum */

typedef short bf16x8 __attribute__((ext_vector_type(8)));
typedef float f32x4  __attribute__((ext_vector_type(4)));
typedef float f32x2  __attribute__((ext_vector_type(2)));   // -> v_pk_* f32 ops

struct F3 { float x, y, z; };   // 12 B -> global_load_dwordx3, coalesced

static __device__ __forceinline__ float bf2f(uint16_t u){
  union{uint32_t i; float f;} v; v.i = ((uint32_t)u) << 16; return v.f;
}
static __device__ __forceinline__ uint16_t f2bf(float f){
  union{uint32_t i; float f;} v; v.f = f;
  uint32_t u = v.i;
  uint32_t r = (u + 0x7FFFu + ((u >> 16) & 1u)) >> 16;   // RNE, finite inputs
  return (uint16_t)r;
}

// One DPP max-combine step on a u64 key (verified bit-exact rounds 9-12).
#define DPP_MAXSTEP(k, CTRL) {                                                   \
  unsigned _lo = (unsigned)(k), _hi = (unsigned)((k) >> 32);                     \
  unsigned _plo = (unsigned)__builtin_amdgcn_update_dpp((int)_lo, (int)_lo,      \
                                                        CTRL, 0xf, 0xf, false); \
  unsigned _phi = (unsigned)__builtin_amdgcn_update_dpp((int)_hi, (int)_hi,      \
                                                        CTRL, 0xf, 0xf, false); \
  unsigned long long _pk = ((unsigned long long)_phi << 32) | _plo;              \
  if(_pk > (k)) (k) = _pk; }

// Build an MFMA A-fragment of h1 = relu(la0*y1 + lb0) in bf16 from the
// TRANSPOSED y1t layout (r19): u32 row c2 holds bf16 pair {2*c2, 2*c2+1} for
// all m (row stride M_). 4 dword loads; each 16-lane row-group reads 64 B
// contiguous. Same bits, same unpack order => bitwise-identical fragments.
static __device__ __forceinline__ bf16x8 h1_frag(const uint16_t* __restrict__ y1t,
                                                 const float* la0s, const float* lb0s,
                                                 int m, int kb){
  const uint32_t* __restrict__ y32 = (const uint32_t*)y1t;
  const int c2 = kb >> 1;
  uint32_t wrd[4];
#pragma unroll
  for(int i = 0; i < 4; ++i) wrd[i] = y32[(size_t)(c2 + i) * M_ + m];
  bf16x8 f;
#pragma unroll
  for(int i = 0; i < 4; ++i){
    int c0 = kb + 2*i;
    float v0 = bf2f((uint16_t)(wrd[i] & 0xFFFFu));
    float v1 = bf2f((uint16_t)(wrd[i] >> 16));
    float h0 = fmaxf(la0s[c0]   * v0 + lb0s[c0],   0.0f);
    float h1 = fmaxf(la0s[c0+1] * v1 + lb0s[c0+1], 0.0f);
    f[2*i]   = (short)f2bf(h0);
    f[2*i+1] = (short)f2bf(h1);
  }
  return f;
}

// ---------------------------------------------------------------------------
// 1) FPS: r12's verified 4-wave loop, split into 4 chunk dispatches of 256
//    iterations — the measured optimum (4x153=612 < monolith 623 < 8-chunk
//    621 < 16-chunk 644). Wave-count curve complete (2w=1865, 4w=1460,
//    16w=1875 cy/iter): 4 waves = 1/SIMD is the issue minimum; structure
//    final. Bit-exact state handoff via dstate/farws (r18-verified).
// ---------------------------------------------------------------------------
__global__ __launch_bounds__(256)
void fps_chunk_kernel(const float* __restrict__ xyz,
                      float* __restrict__ out_newxyz,
                      f32x2* __restrict__ dstate,
                      int* __restrict__ farws,
                      int it0, int itend, int is_first, int is_last){
  const int b = blockIdx.x;
  const int tid = threadIdx.x;
  const float* X = xyz + (size_t)b * N_ * 3;
  __shared__ float4 sxyz[N_];                       // 64 KB coord cache
  __shared__ __align__(16) unsigned long long slots[2][4];
  __shared__ float outbuf[FCH * 3];                 // 3 KB chunk staging
  f32x2 px[8], py[8], pz[8], dist[8];
#pragma unroll
  for(int j = 0; j < 8; ++j){
    int p0 = tid + (2*j)   * 256;
    int p1 = tid + (2*j+1) * 256;
    px[j].x = X[p0*3 + 0]; px[j].y = X[p1*3 + 0];
    py[j].x = X[p0*3 + 1]; py[j].y = X[p1*3 + 1];
    pz[j].x = X[p0*3 + 2]; pz[j].y = X[p1*3 + 2];
    sxyz[p0] = make_float4(px[j].x, py[j].x, pz[j].x, 0.0f);
    sxyz[p1] = make_float4(px[j].y, py[j].y, pz[j].y, 0.0f);
  }
  if(is_first){
#pragma unroll
    for(int j = 0; j < 8; ++j){ dist[j].x = 1e10f; dist[j].y = 1e10f; }
  } else {
#pragma unroll
    for(int j = 0; j < 8; ++j) dist[j] = dstate[((size_t)b*8 + j)*256 + tid];
  }
  int far = is_first ? 0 : farws[b];                // reference: idx[0] = 0
  __syncthreads();
  for(int it = it0; it < itend; ++it){
    float4 c = sxyz[far];                           // broadcast b128 read
    if(tid == 0){                                   // LDS only
      int lo = (it - it0) * 3;
      outbuf[lo + 0] = c.x; outbuf[lo + 1] = c.y; outbuf[lo + 2] = c.z;
    }
    if(it == S_ - 1) break;                         // global last: no update
    f32x2 cx; cx.x = c.x; cx.y = c.x;
    f32x2 cy; cy.x = c.y; cy.y = c.y;
    f32x2 cz; cz.x = c.z; cz.y = c.z;
    float bestd = -1.0f; int bestt = 0;
#pragma unroll
    for(int j = 0; j < 8; ++j){
      f32x2 nd;
      {
#pragma clang fp contract(off)
        f32x2 dx = px[j] - cx, dy = py[j] - cy, dz = pz[j] - cz;
        f32x2 d  = dx*dx + dy*dy + dz*dz;   // ((dx2+dy2)+dz2), same assoc as scalar
        nd = __builtin_elementwise_min(dist[j], d);
      }
      dist[j] = nd;
      if(nd.x > bestd){ bestd = nd.x; bestt = 2*j; }      // t ascending ->
      if(nd.y > bestd){ bestd = nd.y; bestt = 2*j+1; }    // first max kept
    }
    const int bestp = tid + (bestt << 8);
    unsigned long long key = ((unsigned long long)__float_as_uint(bestd) << 32)
                           | (unsigned long long)(uint32_t)(~bestp);
    DPP_MAXSTEP(key, 0x111);
    DPP_MAXSTEP(key, 0x112);
    DPP_MAXSTEP(key, 0x114);
    DPP_MAXSTEP(key, 0x118);
    DPP_MAXSTEP(key, 0x142);
    DPP_MAXSTEP(key, 0x143);                        // lane 63 holds wave max
    const int par = it & 1;
    if((tid & 63) == 63) slots[par][tid >> 6] = key;
    __syncthreads();
    ulonglong2 s01 = *(const ulonglong2*)&slots[par][0];   // 2x ds_read_b128
    ulonglong2 s23 = *(const ulonglong2*)&slots[par][2];
    unsigned long long bk = s01.x;
    if(s01.y > bk) bk = s01.y;
    if(s23.x > bk) bk = s23.x;
    if(s23.y > bk) bk = s23.y;
    far = (int)(~(uint32_t)bk);                     // uniform across block
  }
  if(!is_last){                                     // hand off carried state
#pragma unroll
    for(int j = 0; j < 8; ++j) dstate[((size_t)b*8 + j)*256 + tid] = dist[j];
    if(tid == 0) farws[b] = far;
  }
  __syncthreads();
  float* O = out_newxyz + (size_t)b * S_ * 3 + (size_t)it0 * 3;
  const int cnt = (itend - it0) * 3;                // coalesced chunk drain
  for(int i = tid; i < cnt; i += 256) O[i] = outbuf[i];
}

// ---------------------------------------------------------------------------
// 2) Ball query, fp32 prefilter (r10-verified decisions) + dwordx3 coalesced
//    point loads; block 0 zeroes gstats (r12). Unchanged from r12.
// ---------------------------------------------------------------------------
__global__ __launch_bounds__(256) void ballq_kernel(const float* __restrict__ xyz,
                                                    const float* __restrict__ newxyz,
                                                    int* __restrict__ gidx,
                                                    float* __restrict__ gstats){
  const int tid = threadIdx.x;
  if(blockIdx.x == 0){                // fold: zero stats (512 floats)
    gstats[tid] = 0.0f; gstats[256 + tid] = 0.0f;
  }
  const int wslot = tid >> 6;
  const int lane  = tid & 63;
  const int q = blockIdx.x * 4 + wslot;
  const int b = q >> 10;
  const F3* XP = (const F3*)(xyz + (size_t)b * N_ * 3);
  const double R2D = 0.2 * 0.2;
  float nxf, nyf, nzf, saf;
  double nx, ny, nz, sa;
  {
    const float* NP = newxyz + (size_t)q * 3;
    nxf = NP[0]; nyf = NP[1]; nzf = NP[2];
    saf = nxf*nxf + nyf*nyf + nzf*nzf;
    nx = (double)nxf; ny = (double)nyf; nz = (double)nzf;
    sa = nx*nx + ny*ny + nz*nz;
  }
  __shared__ int sidx[4][K_];
  int count = 0;
  for(int base = 0; base < N_; base += 64){
    int p = base + lane;
    F3 pt = XP[p];                                  // global_load_dwordx3
    float sb32 = pt.x*pt.x + pt.y*pt.y + pt.z*pt.z;
    float dt32 = nxf*pt.x + nyf*pt.y + nzf*pt.z;
    float sq32 = saf + sb32 - 2.0f * dt32;
    bool band = fabsf(sq32 - 0.04f) < 5e-5f;
    bool inb;
    if(__ballot(band) != 0ull){
      double pxv = (double)pt.x, pyv = (double)pt.y, pzv = (double)pt.z;
      double sb = pxv*pxv + pyv*pyv + pzv*pzv;
      double dt = nx*pxv + ny*pyv + nz*pzv;
      double sq = sa + sb - 2.0 * dt;
      inb = !(sq > R2D);
    } else {
      inb = !(sq32 > 0.04f);
    }
    unsigned long long mask = __ballot(inb);
    int pos = count + __popcll(mask & ((1ull << lane) - 1ull));
    if(inb && pos < K_) sidx[wslot][pos] = p;
    count += (int)__popcll(mask);
    if(count >= K_) break;
  }
  __syncthreads();
  int nvalid = count < K_ ? count : K_;
  if(lane < K_){
    int first = sidx[wslot][0];
    int v = (lane < nvalid) ? sidx[wslot][lane] : first;
    gidx[(size_t)q * K_ + lane] = v;
  }
}

// ---------------------------------------------------------------------------
// 3) Layer 1 r21 (verified best: 972.9 total): LDS-tiled fp32 GEMM.
//    128m x 64o tile, 256 threads, 8m x 4o micro-tile -> acc[8][4] = 32
//    VGPRs statically indexed (forced register residency; allocator refused
//    x[67]/acc[64] in r19/r20 at 12-16x the FMA floor). xT[c][m] 34.3KB +
//    wT[c][o] 17.2KB in LDS. r23 (conflict split) and r24 (wT->global)
//    both measured neutral-to-worse => this exact variant is best known.
// ---------------------------------------------------------------------------
__global__ __launch_bounds__(256)
void layer1_kernel(const float* __restrict__ xyz,
                   const float* __restrict__ pts,
                   const float* __restrict__ newxyz,
                   const int* __restrict__ gidx,
                   const float* __restrict__ w,
                   const float* __restrict__ bias,
                   uint16_t* __restrict__ y1t,
                   float* __restrict__ gstats){
  __shared__ float xT[67*128];                      // 34.3 KB  xT[c][m]
  __shared__ float wT[67*64];                       // 17.2 KB  wT[c][o]
  __shared__ float sm_sum[64], sm_sq[64];
  const int tid = threadIdx.x;
  const int bm = blockIdx.x * 128;

  for(int i = tid; i < 67*64; i += 256){            // w: coalesced read,
    int o = i / 67, c = i - o*67;                   // scattered LDS write
    wT[c*64 + o] = w[i];                            // (one-time)
  }
  {                                                 // gather + transpose x
    const int r = tid >> 1, h = tid & 1;            // 2 threads per row
    const int m = bm + r;
    const int bs = m >> 5, b = bs >> 10;
    const int j = gidx[m];
    const float4* pr = (const float4*)(pts + ((size_t)b * N_ + j) * D_);
    if(h == 0){
      const float* nxp = newxyz + (size_t)bs * 3;
      const float* pp  = xyz + ((size_t)b * N_ + j) * 3;
      xT[0*128 + r] = pp[0] - nxp[0];
      xT[1*128 + r] = pp[1] - nxp[1];
      xT[2*128 + r] = pp[2] - nxp[2];
#pragma unroll
      for(int k = 0; k < 8; ++k){
        float4 v = pr[k];
        xT[(3 + 4*k + 0)*128 + r] = v.x; xT[(3 + 4*k + 1)*128 + r] = v.y;
        xT[(3 + 4*k + 2)*128 + r] = v.z; xT[(3 + 4*k + 3)*128 + r] = v.w;
      }
    } else {
#pragma unroll
      for(int k = 8; k < 16; ++k){
        float4 v = pr[k];
        xT[(3 + 4*k + 0)*128 + r] = v.x; xT[(3 + 4*k + 1)*128 + r] = v.y;
        xT[(3 + 4*k + 2)*128 + r] = v.z; xT[(3 + 4*k + 3)*128 + r] = v.w;
      }
    }
  }
  __syncthreads();

  const int mq = tid & 15;                          // 8 m's: mq*8 .. +7
  const int oq = tid >> 4;                          // 4 o's: oq*4 .. +3
  float acc[8][4];
  {
    float4 bv = *(const float4*)&bias[oq*4];
#pragma unroll
    for(int mi = 0; mi < 8; ++mi){
      acc[mi][0] = bv.x; acc[mi][1] = bv.y; acc[mi][2] = bv.z; acc[mi][3] = bv.w;
    }
  }
  for(int c = 0; c < 67; ++c){
    f32x4 xa = *(const f32x4*)&xT[c*128 + mq*8];
    f32x4 xb = *(const f32x4*)&xT[c*128 + mq*8 + 4];
    f32x4 wv = *(const f32x4*)&wT[c*64 + oq*4];
#pragma unroll
    for(int mi = 0; mi < 4; ++mi){
      float xv = xa[mi];
#pragma unroll
      for(int oi = 0; oi < 4; ++oi) acc[mi][oi] = fmaf(wv[oi], xv, acc[mi][oi]);
    }
#pragma unroll
    for(int mi = 4; mi < 8; ++mi){
      float xv = xb[mi-4];
#pragma unroll
      for(int oi = 0; oi < 4; ++oi) acc[mi][oi] = fmaf(wv[oi], xv, acc[mi][oi]);
    }
  }

  // stats: fold mi, then shuffle-reduce across mq (lane low 4 bits)
  {
    float s[4], q[4];
#pragma unroll
    for(int oi = 0; oi < 4; ++oi){
      float ss = 0.f, qq = 0.f;
#pragma unroll
      for(int mi = 0; mi < 8; ++mi){
        ss += acc[mi][oi]; qq = fmaf(acc[mi][oi], acc[mi][oi], qq);
      }
      s[oi] = ss; q[oi] = qq;
    }
#pragma unroll
    for(int d = 1; d < 16; d <<= 1){
#pragma unroll
      for(int oi = 0; oi < 4; ++oi){
        s[oi] += __shfl_xor(s[oi], d, 64);
        q[oi] += __shfl_xor(q[oi], d, 64);
      }
    }
    if(mq == 0){
#pragma unroll
      for(int oi = 0; oi < 4; ++oi){
        sm_sum[oq*4 + oi] = s[oi];                  // unique writer per o
        sm_sq [oq*4 + oi] = q[oi];
      }
    }
  }

  // y1 store: transposed u32 pairs, 8 consecutive m -> 2x dwordx4 per o2
  {
    uint32_t* __restrict__ y1o = (uint32_t*)y1t;
#pragma unroll
    for(int p = 0; p < 2; ++p){
      uint32_t pk[8];
#pragma unroll
      for(int mi = 0; mi < 8; ++mi){
        uint32_t lo = (uint32_t)f2bf(acc[mi][2*p]);
        uint32_t hi = (uint32_t)f2bf(acc[mi][2*p + 1]);
        pk[mi] = lo | (hi << 16);
      }
      uint32_t* dst = &y1o[(size_t)(oq*2 + p) * M_ + bm + mq*8];
      *(uint4*)(dst)     = make_uint4(pk[0], pk[1], pk[2], pk[3]);
      *(uint4*)(dst + 4) = make_uint4(pk[4], pk[5], pk[6], pk[7]);
    }
  }
  __syncthreads();
  if(tid < 64)       atomicAdd(&gstats[tid],      sm_sum[tid]);
  else if(tid < 128) atomicAdd(&gstats[tid],      sm_sq[tid - 64]);
}

// ---------------------------------------------------------------------------
// 4) Layer 2 stats via MFMA, 512 m/block (r12). Same mfma order as layer3's
//    recompute => bitwise-identical z2. Reads transposed y1t via h1_frag.
// ---------------------------------------------------------------------------
__global__ __launch_bounds__(256)
void layer2_stats_kernel(const uint16_t* __restrict__ y1t,
                         const float* __restrict__ gstats0,
                         const float* __restrict__ g0,
                         const float* __restrict__ bt0,
                         const float* __restrict__ w1,
                         const float* __restrict__ b1,
                         float* __restrict__ gstats1){
  __shared__ short w1b[64*WPAD];
  __shared__ float la0s[64], lb0s[64], b1s[64];
  __shared__ float ssum[64], ssq[64];
  const int tid = threadIdx.x;
#pragma unroll
  for(int i = 0; i < 16; ++i){
    int e = i*256 + tid;
    w1b[(e>>6)*WPAD + (e&63)] = (short)f2bf(w1[e]);
  }
  if(tid < 64){
    float mean = gstats0[tid] * (1.0f / M_);
    float var  = gstats0[64 + tid] * (1.0f / M_) - mean * mean;
    float inv  = 1.0f / sqrtf(var + EPS_);
    float a = g0[tid] * inv;
    la0s[tid] = a; lb0s[tid] = bt0[tid] - mean * a;
    b1s[tid] = b1[tid];
  } else if(tid < 128){
    ssum[tid-64] = 0.f; ssq[tid-64] = 0.f;
  }
  __syncthreads();

  const int wave = tid >> 6, lane = tid & 63;
  const int row = lane & 15, quad = lane >> 4;

  for(int ck = 0; ck < 4; ++ck){
    const int wm0 = blockIdx.x * 512 + ck * 128 + wave * 32;
    bf16x8 afr[2][2];
#pragma unroll
    for(int s = 0; s < 2; ++s)
#pragma unroll
      for(int k2 = 0; k2 < 2; ++k2)
        afr[s][k2] = h1_frag(y1t, la0s, lb0s, wm0 + s*16 + row, quad*8 + k2*32);

    for(int ot = 0; ot < 4; ++ot){
      bf16x8 bfr0 = *(const bf16x8*)&w1b[(ot*16 + row)*WPAD + quad*8];
      bf16x8 bfr1 = *(const bf16x8*)&w1b[(ot*16 + row)*WPAD + quad*8 + 32];
      const float bb = b1s[ot*16 + row];
      float sum_ = 0.f, sq_ = 0.f;
#pragma unroll
      for(int s = 0; s < 2; ++s){
        f32x4 acc = {0.f, 0.f, 0.f, 0.f};
        acc = __builtin_amdgcn_mfma_f32_16x16x32_bf16(afr[s][0], bfr0, acc, 0, 0, 0);
        acc = __builtin_amdgcn_mfma_f32_16x16x32_bf16(afr[s][1], bfr1, acc, 0, 0, 0);
#pragma unroll
        for(int r = 0; r < 4; ++r){
          float z = acc[r] + bb;
          sum_ += z; sq_ = fmaf(z, z, sq_);
        }
      }
      sum_ += __shfl_xor(sum_, 16, 64); sum_ += __shfl_xor(sum_, 32, 64);
      sq_  += __shfl_xor(sq_,  16, 64); sq_  += __shfl_xor(sq_,  32, 64);
      if(quad == 0){
        atomicAdd(&ssum[ot*16 + row], sum_);
        atomicAdd(&ssq [ot*16 + row], sq_);
      }
    }
  }
  __syncthreads();
  if(tid < 64)       atomicAdd(&gstats1[tid], ssum[tid]);
  else if(tid < 128) atomicAdd(&gstats1[tid], ssq[tid - 64]);
}

// ---------------------------------------------------------------------------
// 5) Layer 3 via MFMA, 512 m/block (r12). h2 staging wave-private; same mfma
//    order as layer2_stats; fused stats2 + k-group max/min. Transposed y1t.
// ---------------------------------------------------------------------------
__global__ __launch_bounds__(256)
void layer3_kernel(const uint16_t* __restrict__ y1t,
                   const float* __restrict__ gstats0,
                   const float* __restrict__ g0,
                   const float* __restrict__ bt0,
                   const float* __restrict__ w1,
                   const float* __restrict__ b1,
                   const float* __restrict__ gstats1,
                   const float* __restrict__ g1,
                   const float* __restrict__ bt1,
                   const float* __restrict__ w2,
                   const float* __restrict__ b2,
                   float* __restrict__ gstats2,
                   float* __restrict__ maxk,
                   float* __restrict__ mink){
  __shared__ short w1b[64*WPAD];
  __shared__ short w2b[128*WPAD];
  __shared__ short h2s[4][32*WPAD];
  __shared__ float la0s[64], lb0s[64], la1s[64], lb1s[64], b1s[64], b2s[128];
  __shared__ float ssum[128], ssq[128];
  const int tid = threadIdx.x;
#pragma unroll
  for(int i = 0; i < 16; ++i){
    int e = i*256 + tid;
    w1b[(e>>6)*WPAD + (e&63)] = (short)f2bf(w1[e]);
  }
#pragma unroll
  for(int i = 0; i < 32; ++i){
    int e = i*256 + tid;
    w2b[(e>>6)*WPAD + (e&63)] = (short)f2bf(w2[e]);
  }
  if(tid < 64){
    float mean = gstats0[tid] * (1.0f / M_);
    float var  = gstats0[64 + tid] * (1.0f / M_) - mean * mean;
    float inv  = 1.0f / sqrtf(var + EPS_);
    float a = g0[tid] * inv;
    la0s[tid] = a; lb0s[tid] = bt0[tid] - mean * a;
    b1s[tid] = b1[tid];
  } else if(tid < 128){
    int o = tid - 64;
    float mean = gstats1[o] * (1.0f / M_);
    float var  = gstats1[64 + o] * (1.0f / M_) - mean * mean;
    float inv  = 1.0f / sqrtf(var + EPS_);
    float a = g1[o] * inv;
    la1s[o] = a; lb1s[o] = bt1[o] - mean * a;
  }
  if(tid < 128){ b2s[tid] = b2[tid]; ssum[tid] = 0.f; }
  else         { ssq[tid - 128] = 0.f; }
  __syncthreads();

  const int wave = tid >> 6, lane = tid & 63;
  const int row = lane & 15, quad = lane >> 4;
  short* h2w = &h2s[wave][0];

  for(int ck = 0; ck < 4; ++ck){
    const int wm0 = blockIdx.x * 512 + ck * 128 + wave * 32;
    {
      bf16x8 afr[2][2];
#pragma unroll
      for(int s = 0; s < 2; ++s)
#pragma unroll
        for(int k2 = 0; k2 < 2; ++k2)
          afr[s][k2] = h1_frag(y1t, la0s, lb0s, wm0 + s*16 + row, quad*8 + k2*32);

      for(int ot = 0; ot < 4; ++ot){
        bf16x8 bfr0 = *(const bf16x8*)&w1b[(ot*16 + row)*WPAD + quad*8];
        bf16x8 bfr1 = *(const bf16x8*)&w1b[(ot*16 + row)*WPAD + quad*8 + 32];
        const int o = ot*16 + row;
        const float bb = b1s[o], a1 = la1s[o], c1 = lb1s[o];
#pragma unroll
        for(int s = 0; s < 2; ++s){
          f32x4 acc = {0.f, 0.f, 0.f, 0.f};
          acc = __builtin_amdgcn_mfma_f32_16x16x32_bf16(afr[s][0], bfr0, acc, 0, 0, 0);
          acc = __builtin_amdgcn_mfma_f32_16x16x32_bf16(afr[s][1], bfr1, acc, 0, 0, 0);
#pragma unroll
          for(int r = 0; r < 4; ++r){
            float z = acc[r] + bb;
            float h = fmaxf(a1 * z + c1, 0.0f);
            int ml = s*16 + quad*4 + r;
            h2w[ml*WPAD + o] = (short)f2bf(h);
          }
        }
      }
    }
    {
      bf16x8 hfr[2][2];
#pragma unroll
      for(int s = 0; s < 2; ++s)
#pragma unroll
        for(int k2 = 0; k2 < 2; ++k2)
          hfr[s][k2] = *(const bf16x8*)&h2w[(s*16 + row)*WPAD + quad*8 + k2*32];

      for(int ot = 0; ot < 8; ++ot){
        bf16x8 bfr0 = *(const bf16x8*)&w2b[(ot*16 + row)*WPAD + quad*8];
        bf16x8 bfr1 = *(const bf16x8*)&w2b[(ot*16 + row)*WPAD + quad*8 + 32];
        const int o = ot*16 + row;
        const float bb = b2s[o];
        float sum_ = 0.f, sq_ = 0.f, mx = -1e30f, mn = 1e30f;
#pragma unroll
        for(int s = 0; s < 2; ++s){
          f32x4 acc = {0.f, 0.f, 0.f, 0.f};
          acc = __builtin_amdgcn_mfma_f32_16x16x32_bf16(hfr[s][0], bfr0, acc, 0, 0, 0);
          acc = __builtin_amdgcn_mfma_f32_16x16x32_bf16(hfr[s][1], bfr1, acc, 0, 0, 0);
#pragma unroll
          for(int r = 0; r < 4; ++r){
            float z = acc[r] + bb;
            sum_ += z; sq_ = fmaf(z, z, sq_);
            mx = fmaxf(mx, z); mn = fminf(mn, z);
          }
        }
        sum_ += __shfl_xor(sum_, 16, 64); sum_ += __shfl_xor(sum_, 32, 64);
        sq_  += __shfl_xor(sq_,  16, 64); sq_  += __shfl_xor(sq_,  32, 64);
        mx = fmaxf(mx, __shfl_xor(mx, 16, 64)); mx = fmaxf(mx, __shfl_xor(mx, 32, 64));
        mn = fminf(mn, __shfl_xor(mn, 16, 64)); mn = fminf(mn, __shfl_xor(mn, 32, 64));
        if(quad == 0){
          atomicAdd(&ssum[o], sum_);
          atomicAdd(&ssq [o], sq_);
          maxk[(size_t)(wm0 >> 5) * 128 + o] = mx;
          mink[(size_t)(wm0 >> 5) * 128 + o] = mn;
        }
      }
    }
  }
  __syncthreads();
  if(tid < 128) atomicAdd(&gstats2[tid], ssum[tid]);
  else          atomicAdd(&gstats2[tid], ssq[tid - 128]);
}

// ---------------------------------------------------------------------------
// 6) Final: BN2+ReLU on max/min endpoints. Unchanged.
// ---------------------------------------------------------------------------
__global__ __launch_bounds__(256) void final_kernel(const float* __restrict__ maxk,
                                                    const float* __restrict__ mink,
                                                    const float* __restrict__ gstats2,
                                                    const float* __restrict__ g,
                                                    const float* __restrict__ bt,
                                                    float* __restrict__ out_np){
  const int gid = blockIdx.x * 256 + threadIdx.x;
  const int o = gid & 127;
  float mean = gstats2[o] * (1.0f / M_);
  float var  = gstats2[128 + o] * (1.0f / M_) - mean * mean;
  float inv  = 1.0f / sqrtf(var + EPS_);
  float a = g[o] * inv;
  float b = bt[o] - mean * a;
  float mx = maxk[gid], mn = mink[gid];
  out_np[gid] = fmaxf(fmaxf(a * mx + b, 0.0f), fmaxf(a * mn + b, 0.0f));
}

// ---------------------------------------------------------------------------
extern "C" void kernel_launch(void* const* d_in, const int* in_sizes, int n_in,
                              void* d_out, int out_size, void* d_ws, size_t ws_size,
                              hipStream_t stream){
  (void)in_sizes; (void)n_in; (void)out_size;
  const float* xyz = (const float*)d_in[0];
  const float* pts = (const float*)d_in[1];
  const float* w0 = (const float*)d_in[2];  const float* b0  = (const float*)d_in[3];
  const float* g0 = (const float*)d_in[4];  const float* bt0 = (const float*)d_in[5];
  const float* w1 = (const float*)d_in[6];  const float* b1  = (const float*)d_in[7];
  const float* g1 = (const float*)d_in[8];  const float* bt1 = (const float*)d_in[9];
  const float* w2 = (const float*)d_in[10]; const float* b2  = (const float*)d_in[11];
  const float* g2 = (const float*)d_in[12]; const float* bt2 = (const float*)d_in[13];

  float* out    = (float*)d_out;
  float* newxyz = out;                       // (B,S,3)
  float* newpts = out + (size_t)B_ * S_ * 3; // (B,S,128)

  const size_t off_gidx  = 0;
  const size_t off_stats = off_gidx  + (size_t)M_ * 4;
  const size_t off_maxk  = off_stats + 65536;
  const size_t off_mink  = off_maxk  + (size_t)NQ_ * 128 * 4;
  const size_t off_y1    = off_mink  + (size_t)NQ_ * 128 * 4;
  const size_t off_fd    = off_y1    + (size_t)M_ * 64 * 2;   // fps dist state
  const size_t off_ff    = off_fd    + (size_t)B_ * 8 * 256 * 8; // fps far
  const size_t need      = off_ff    + 256;
  if(ws_size < need) return;

  char* ws = (char*)d_ws;
  int*      gidx   = (int*)     (ws + off_gidx);
  float*    gstats = (float*)   (ws + off_stats);
  float*    maxk   = (float*)   (ws + off_maxk);
  float*    mink   = (float*)   (ws + off_mink);
  uint16_t* y1t    = (uint16_t*)(ws + off_y1);
  f32x2*    dstate = (f32x2*)   (ws + off_fd);
  int*      farws  = (int*)     (ws + off_ff);

  for(int k = 0; k < 4; ++k){
    fps_chunk_kernel<<<B_, 256, 0, stream>>>(xyz, newxyz, dstate, farws,
                                             k*FCH, (k+1)*FCH,
                                             k == 0 ? 1 : 0, k == 3 ? 1 : 0);
  }
  ballq_kernel<<<NQ_ / 4, 256, 0, stream>>>(xyz, newxyz, gidx, gstats);

  layer1_kernel      <<<M_ / 128, 256, 0, stream>>>(xyz, pts, newxyz, gidx, w0, b0, y1t, gstats);
  layer2_stats_kernel<<<M_ / 512, 256, 0, stream>>>(y1t, gstats, g0, bt0, w1, b1, gstats + 128);
  layer3_kernel      <<<M_ / 512, 256, 0, stream>>>(y1t, gstats, g0, bt0, w1, b1,
                                                    gstats + 128, g1, bt1, w2, b2,
                                                    gstats + 256, maxk, mink);
  final_kernel<<<(NQ_ * 128) / 256, 256, 0, stream>>>(maxk, mink, gstats + 256, g2, bt2, newpts);
}

// Round 16
// 919.458 us; speedup vs baseline: 1.0950x; 1.0558x over previous
//
#include <hip/hip_runtime.h>
#include <stdint.h>

#define B_ 16
#define N_ 4096
#define D_ 64
#define S_ 1024
#define K_ 32
#define M_ (B_*S_*K_)   /* 524288 */
#define NQ_ (B_*S_)     /* 16384 */
#define EPS_ 1e-5f
#define WPAD 72         /* bf16 LDS row stride: 72*2=144 B, 16B-aligned frags */
#define FCH 256         /* fps chunk length: 4 chunks = measured optimum */
#define NBQ_ 1024       /* ballq blocks per quarter: (NQ_/4)/4 */
#define NL1_ 1024       /* layer1 blocks per quarter: (M_/4)/128 */

typedef short bf16x8 __attribute__((ext_vector_type(8)));
typedef float f32x4  __attribute__((ext_vector_type(4)));
typedef float f32x2  __attribute__((ext_vector_type(2)));   // -> v_pk_* f32 ops

struct F3 { float x, y, z; };   // 12 B -> global_load_dwordx3, coalesced

static __device__ __forceinline__ float bf2f(uint16_t u){
  union{uint32_t i; float f;} v; v.i = ((uint32_t)u) << 16; return v.f;
}
static __device__ __forceinline__ uint16_t f2bf(float f){
  union{uint32_t i; float f;} v; v.f = f;
  uint32_t u = v.i;
  uint32_t r = (u + 0x7FFFu + ((u >> 16) & 1u)) >> 16;   // RNE, finite inputs
  return (uint16_t)r;
}

// One DPP max-combine step on a u64 key (verified bit-exact rounds 9-12).
#define DPP_MAXSTEP(k, CTRL) {                                                   \
  unsigned _lo = (unsigned)(k), _hi = (unsigned)((k) >> 32);                     \
  unsigned _plo = (unsigned)__builtin_amdgcn_update_dpp((int)_lo, (int)_lo,      \
                                                        CTRL, 0xf, 0xf, false); \
  unsigned _phi = (unsigned)__builtin_amdgcn_update_dpp((int)_hi, (int)_hi,      \
                                                        CTRL, 0xf, 0xf, false); \
  unsigned long long _pk = ((unsigned long long)_phi << 32) | _plo;              \
  if(_pk > (k)) (k) = _pk; }

// Build an MFMA A-fragment of h1 = relu(la0*y1 + lb0) in bf16 from the
// TRANSPOSED y1t layout (r19): u32 row c2 holds bf16 pair {2*c2, 2*c2+1} for
// all m (row stride M_). Bit-identical fragments (verified r19+).
static __device__ __forceinline__ bf16x8 h1_frag(const uint16_t* __restrict__ y1t,
                                                 const float* la0s, const float* lb0s,
                                                 int m, int kb){
  const uint32_t* __restrict__ y32 = (const uint32_t*)y1t;
  const int c2 = kb >> 1;
  uint32_t wrd[4];
#pragma unroll
  for(int i = 0; i < 4; ++i) wrd[i] = y32[(size_t)(c2 + i) * M_ + m];
  bf16x8 f;
#pragma unroll
  for(int i = 0; i < 4; ++i){
    int c0 = kb + 2*i;
    float v0 = bf2f((uint16_t)(wrd[i] & 0xFFFFu));
    float v1 = bf2f((uint16_t)(wrd[i] >> 16));
    float h0 = fmaxf(la0s[c0]   * v0 + lb0s[c0],   0.0f);
    float h1 = fmaxf(la0s[c0+1] * v1 + lb0s[c0+1], 0.0f);
    f[2*i]   = (short)f2bf(h0);
    f[2*i+1] = (short)f2bf(h1);
  }
  return f;
}

// ---------------------------------------------------------------------------
// r27 FUSED pipeline kernel. During fps, 240/256 CUs were idle (fps = 16
// blocks, 612us = 63% of runtime). fps chunk k produces centroids s in
// [k*256,(k+1)*256) for ALL batches; ballq needs only its own centroid and
// layer1 only its own gidx row -> quarters of ballq/layer1 ride in the SAME
// dispatch as the next fps chunk (fps = blocks 0..15, dispatched first).
// All producer->consumer edges remain at kernel-launch boundaries (same-
// stream coherence); no new intra-kernel communication; arithmetic is
// byte-identical to r21 => bit-exact. LDS = static 68672B union (= proven
// fps chunk footprint; layer1's 51968 fits inside).
//   L1 fps0 | L2 fps1+bq0 | L3 fps2+bq1+l1q0 | L4 fps3+bq2+l1q1
//   L5 bq3+l1q2 | L6 l1q3 | then layer2/layer3/final unchanged.
// ---------------------------------------------------------------------------
__global__ __launch_bounds__(256)
void fused_kernel(const float* __restrict__ xyz,
                  const float* __restrict__ pts,
                  float* __restrict__ out_newxyz,
                  f32x2* __restrict__ dstate,
                  int* __restrict__ farws,
                  int* __restrict__ gidx,
                  float* __restrict__ gstats,
                  const float* __restrict__ w,
                  const float* __restrict__ bias,
                  uint16_t* __restrict__ y1t,
                  int nfps, int it0, int itend, int is_first, int is_last,
                  int nbq, int bq_qoff, int bq_zero,
                  int l1_qoff){
  __shared__ __align__(16) char smem[68672];
  const int bid = blockIdx.x;
  const int tid = threadIdx.x;

  if(bid < nfps){
    // ---------------- FPS role (r12 4-wave loop, bit-exact handoff) -------
    const int b = bid;
    const float* X = xyz + (size_t)b * N_ * 3;
    float4* sxyz = (float4*)smem;                               // 64 KB
    unsigned long long* slots = (unsigned long long*)(smem + 65536); // 64 B
    float* outbuf = (float*)(smem + 65600);                     // 3 KB
    f32x2 px[8], py[8], pz[8], dist[8];
#pragma unroll
    for(int j = 0; j < 8; ++j){
      int p0 = tid + (2*j)   * 256;
      int p1 = tid + (2*j+1) * 256;
      px[j].x = X[p0*3 + 0]; px[j].y = X[p1*3 + 0];
      py[j].x = X[p0*3 + 1]; py[j].y = X[p1*3 + 1];
      pz[j].x = X[p0*3 + 2]; pz[j].y = X[p1*3 + 2];
      sxyz[p0] = make_float4(px[j].x, py[j].x, pz[j].x, 0.0f);
      sxyz[p1] = make_float4(px[j].y, py[j].y, pz[j].y, 0.0f);
    }
    if(is_first){
#pragma unroll
      for(int j = 0; j < 8; ++j){ dist[j].x = 1e10f; dist[j].y = 1e10f; }
    } else {
#pragma unroll
      for(int j = 0; j < 8; ++j) dist[j] = dstate[((size_t)b*8 + j)*256 + tid];
    }
    int far = is_first ? 0 : farws[b];              // reference: idx[0] = 0
    __syncthreads();
    for(int it = it0; it < itend; ++it){
      float4 c = sxyz[far];                         // broadcast b128 read
      if(tid == 0){                                 // LDS only
        int lo = (it - it0) * 3;
        outbuf[lo + 0] = c.x; outbuf[lo + 1] = c.y; outbuf[lo + 2] = c.z;
      }
      if(it == S_ - 1) break;                       // global last: no update
      f32x2 cx; cx.x = c.x; cx.y = c.x;
      f32x2 cy; cy.x = c.y; cy.y = c.y;
      f32x2 cz; cz.x = c.z; cz.y = c.z;
      float bestd = -1.0f; int bestt = 0;
#pragma unroll
      for(int j = 0; j < 8; ++j){
        f32x2 nd;
        {
#pragma clang fp contract(off)
          f32x2 dx = px[j] - cx, dy = py[j] - cy, dz = pz[j] - cz;
          f32x2 d  = dx*dx + dy*dy + dz*dz; // ((dx2+dy2)+dz2), scalar assoc
          nd = __builtin_elementwise_min(dist[j], d);
        }
        dist[j] = nd;
        if(nd.x > bestd){ bestd = nd.x; bestt = 2*j; }    // t ascending ->
        if(nd.y > bestd){ bestd = nd.y; bestt = 2*j+1; }  // first max kept
      }
      const int bestp = tid + (bestt << 8);
      unsigned long long key = ((unsigned long long)__float_as_uint(bestd) << 32)
                             | (unsigned long long)(uint32_t)(~bestp);
      DPP_MAXSTEP(key, 0x111);
      DPP_MAXSTEP(key, 0x112);
      DPP_MAXSTEP(key, 0x114);
      DPP_MAXSTEP(key, 0x118);
      DPP_MAXSTEP(key, 0x142);
      DPP_MAXSTEP(key, 0x143);                      // lane 63 holds wave max
      const int par = it & 1;
      if((tid & 63) == 63) slots[par*4 + (tid >> 6)] = key;
      __syncthreads();
      ulonglong2 s01 = *(const ulonglong2*)&slots[par*4];     // 2x b128
      ulonglong2 s23 = *(const ulonglong2*)&slots[par*4 + 2];
      unsigned long long bk = s01.x;
      if(s01.y > bk) bk = s01.y;
      if(s23.x > bk) bk = s23.x;
      if(s23.y > bk) bk = s23.y;
      far = (int)(~(uint32_t)bk);                   // uniform across block
    }
    if(!is_last){                                   // hand off carried state
#pragma unroll
      for(int j = 0; j < 8; ++j) dstate[((size_t)b*8 + j)*256 + tid] = dist[j];
      if(tid == 0) farws[b] = far;
    }
    __syncthreads();
    float* O = out_newxyz + (size_t)b * S_ * 3 + (size_t)it0 * 3;
    const int cnt = (itend - it0) * 3;              // coalesced chunk drain
    for(int i = tid; i < cnt; i += 256) O[i] = outbuf[i];

  } else if(bid < nfps + nbq){
    // ---------------- Ball-query role (r12 body; quarter via bq_qoff) ----
    const int local = bid - nfps;
    int* sidx = (int*)smem;                         // [4][K_]
    if(bq_zero && local == 0){                      // zero stats once
      gstats[tid] = 0.0f; gstats[256 + tid] = 0.0f;
    }
    const int wslot = tid >> 6;
    const int lane  = tid & 63;
    const int t = local * 4 + wslot;                // quarter-local query
    const int q = ((t >> 8) << 10) + bq_qoff + (t & 255);
    const int b = q >> 10;
    const F3* XP = (const F3*)(xyz + (size_t)b * N_ * 3);
    const double R2D = 0.2 * 0.2;
    float nxf, nyf, nzf, saf;
    double nx, ny, nz, sa;
    {
      const float* NP = out_newxyz + (size_t)q * 3;
      nxf = NP[0]; nyf = NP[1]; nzf = NP[2];
      saf = nxf*nxf + nyf*nyf + nzf*nzf;
      nx = (double)nxf; ny = (double)nyf; nz = (double)nzf;
      sa = nx*nx + ny*ny + nz*nz;
    }
    int count = 0;
    for(int base = 0; base < N_; base += 64){
      int p = base + lane;
      F3 pt = XP[p];                                // global_load_dwordx3
      float sb32 = pt.x*pt.x + pt.y*pt.y + pt.z*pt.z;
      float dt32 = nxf*pt.x + nyf*pt.y + nzf*pt.z;
      float sq32 = saf + sb32 - 2.0f * dt32;
      bool band = fabsf(sq32 - 0.04f) < 5e-5f;
      bool inb;
      if(__ballot(band) != 0ull){
        double pxv = (double)pt.x, pyv = (double)pt.y, pzv = (double)pt.z;
        double sb = pxv*pxv + pyv*pyv + pzv*pzv;
        double dt = nx*pxv + ny*pyv + nz*pzv;
        double sq = sa + sb - 2.0 * dt;
        inb = !(sq > R2D);
      } else {
        inb = !(sq32 > 0.04f);
      }
      unsigned long long mask = __ballot(inb);
      int pos = count + __popcll(mask & ((1ull << lane) - 1ull));
      if(inb && pos < K_) sidx[wslot*K_ + pos] = p;
      count += (int)__popcll(mask);
      if(count >= K_) break;
    }
    __syncthreads();
    int nvalid = count < K_ ? count : K_;
    if(lane < K_){
      int first = sidx[wslot*K_ + 0];
      int v = (lane < nvalid) ? sidx[wslot*K_ + lane] : first;
      gidx[(size_t)q * K_ + lane] = v;
    }

  } else {
    // ---------------- Layer1 role (r21 body; quarter via l1_qoff) --------
    const int local = bid - nfps - nbq;
    float* xT     = (float*)smem;                   // 34304 B  xT[c][m]
    float* wT     = (float*)(smem + 34304);         // 17152 B  wT[c][o]
    float* sm_sum = (float*)(smem + 51456);         // 256 B
    float* sm_sq  = (float*)(smem + 51712);         // 256 B
    const int tq = local * 4;                       // 4 queries per block
    const int q0 = ((tq >> 8) << 10) + l1_qoff + (tq & 255);
    const int bm = q0 * 32;                         // 128 consecutive m

    for(int i = tid; i < 67*64; i += 256){          // w: coalesced read,
      int o = i / 67, c = i - o*67;                 // scattered LDS write
      wT[c*64 + o] = w[i];                          // (one-time)
    }
    {                                               // gather + transpose x
      const int r = tid >> 1, h = tid & 1;          // 2 threads per row
      const int m = bm + r;
      const int bs = m >> 5, b = bs >> 10;
      const int j = gidx[m];
      const float4* pr = (const float4*)(pts + ((size_t)b * N_ + j) * D_);
      if(h == 0){
        const float* nxp = out_newxyz + (size_t)bs * 3;
        const float* pp  = xyz + ((size_t)b * N_ + j) * 3;
        xT[0*128 + r] = pp[0] - nxp[0];
        xT[1*128 + r] = pp[1] - nxp[1];
        xT[2*128 + r] = pp[2] - nxp[2];
#pragma unroll
        for(int k = 0; k < 8; ++k){
          float4 v = pr[k];
          xT[(3 + 4*k + 0)*128 + r] = v.x; xT[(3 + 4*k + 1)*128 + r] = v.y;
          xT[(3 + 4*k + 2)*128 + r] = v.z; xT[(3 + 4*k + 3)*128 + r] = v.w;
        }
      } else {
#pragma unroll
        for(int k = 8; k < 16; ++k){
          float4 v = pr[k];
          xT[(3 + 4*k + 0)*128 + r] = v.x; xT[(3 + 4*k + 1)*128 + r] = v.y;
          xT[(3 + 4*k + 2)*128 + r] = v.z; xT[(3 + 4*k + 3)*128 + r] = v.w;
        }
      }
    }
    __syncthreads();

    const int mq = tid & 15;                        // 8 m's: mq*8 .. +7
    const int oq = tid >> 4;                        // 4 o's: oq*4 .. +3
    float acc[8][4];
    {
      float4 bv = *(const float4*)&bias[oq*4];
#pragma unroll
      for(int mi = 0; mi < 8; ++mi){
        acc[mi][0] = bv.x; acc[mi][1] = bv.y; acc[mi][2] = bv.z; acc[mi][3] = bv.w;
      }
    }
    for(int c = 0; c < 67; ++c){
      f32x4 xa = *(const f32x4*)&xT[c*128 + mq*8];
      f32x4 xb = *(const f32x4*)&xT[c*128 + mq*8 + 4];
      f32x4 wv = *(const f32x4*)&wT[c*64 + oq*4];
#pragma unroll
      for(int mi = 0; mi < 4; ++mi){
        float xv = xa[mi];
#pragma unroll
        for(int oi = 0; oi < 4; ++oi) acc[mi][oi] = fmaf(wv[oi], xv, acc[mi][oi]);
      }
#pragma unroll
      for(int mi = 4; mi < 8; ++mi){
        float xv = xb[mi-4];
#pragma unroll
        for(int oi = 0; oi < 4; ++oi) acc[mi][oi] = fmaf(wv[oi], xv, acc[mi][oi]);
      }
    }

    // stats: fold mi, then shuffle-reduce across mq (lane low 4 bits)
    {
      float s[4], qv[4];
#pragma unroll
      for(int oi = 0; oi < 4; ++oi){
        float ss = 0.f, qq = 0.f;
#pragma unroll
        for(int mi = 0; mi < 8; ++mi){
          ss += acc[mi][oi]; qq = fmaf(acc[mi][oi], acc[mi][oi], qq);
        }
        s[oi] = ss; qv[oi] = qq;
      }
#pragma unroll
      for(int d = 1; d < 16; d <<= 1){
#pragma unroll
        for(int oi = 0; oi < 4; ++oi){
          s[oi]  += __shfl_xor(s[oi],  d, 64);
          qv[oi] += __shfl_xor(qv[oi], d, 64);
        }
      }
      if(mq == 0){
#pragma unroll
        for(int oi = 0; oi < 4; ++oi){
          sm_sum[oq*4 + oi] = s[oi];                // unique writer per o
          sm_sq [oq*4 + oi] = qv[oi];
        }
      }
    }

    // y1 store: transposed u32 pairs, 8 consecutive m -> 2x dwordx4 per o2
    {
      uint32_t* __restrict__ y1o = (uint32_t*)y1t;
#pragma unroll
      for(int p = 0; p < 2; ++p){
        uint32_t pk[8];
#pragma unroll
        for(int mi = 0; mi < 8; ++mi){
          uint32_t lo = (uint32_t)f2bf(acc[mi][2*p]);
          uint32_t hi = (uint32_t)f2bf(acc[mi][2*p + 1]);
          pk[mi] = lo | (hi << 16);
        }
        uint32_t* dst = &y1o[(size_t)(oq*2 + p) * M_ + bm + mq*8];
        *(uint4*)(dst)     = make_uint4(pk[0], pk[1], pk[2], pk[3]);
        *(uint4*)(dst + 4) = make_uint4(pk[4], pk[5], pk[6], pk[7]);
      }
    }
    __syncthreads();
    if(tid < 64)       atomicAdd(&gstats[tid],      sm_sum[tid]);
    else if(tid < 128) atomicAdd(&gstats[tid],      sm_sq[tid - 64]);
  }
}

// ---------------------------------------------------------------------------
// 4) Layer 2 stats via MFMA, 512 m/block (r12). Same mfma order as layer3's
//    recompute => bitwise-identical z2. Reads transposed y1t via h1_frag.
// ---------------------------------------------------------------------------
__global__ __launch_bounds__(256)
void layer2_stats_kernel(const uint16_t* __restrict__ y1t,
                         const float* __restrict__ gstats0,
                         const float* __restrict__ g0,
                         const float* __restrict__ bt0,
                         const float* __restrict__ w1,
                         const float* __restrict__ b1,
                         float* __restrict__ gstats1){
  __shared__ short w1b[64*WPAD];
  __shared__ float la0s[64], lb0s[64], b1s[64];
  __shared__ float ssum[64], ssq[64];
  const int tid = threadIdx.x;
#pragma unroll
  for(int i = 0; i < 16; ++i){
    int e = i*256 + tid;
    w1b[(e>>6)*WPAD + (e&63)] = (short)f2bf(w1[e]);
  }
  if(tid < 64){
    float mean = gstats0[tid] * (1.0f / M_);
    float var  = gstats0[64 + tid] * (1.0f / M_) - mean * mean;
    float inv  = 1.0f / sqrtf(var + EPS_);
    float a = g0[tid] * inv;
    la0s[tid] = a; lb0s[tid] = bt0[tid] - mean * a;
    b1s[tid] = b1[tid];
  } else if(tid < 128){
    ssum[tid-64] = 0.f; ssq[tid-64] = 0.f;
  }
  __syncthreads();

  const int wave = tid >> 6, lane = tid & 63;
  const int row = lane & 15, quad = lane >> 4;

  for(int ck = 0; ck < 4; ++ck){
    const int wm0 = blockIdx.x * 512 + ck * 128 + wave * 32;
    bf16x8 afr[2][2];
#pragma unroll
    for(int s = 0; s < 2; ++s)
#pragma unroll
      for(int k2 = 0; k2 < 2; ++k2)
        afr[s][k2] = h1_frag(y1t, la0s, lb0s, wm0 + s*16 + row, quad*8 + k2*32);

    for(int ot = 0; ot < 4; ++ot){
      bf16x8 bfr0 = *(const bf16x8*)&w1b[(ot*16 + row)*WPAD + quad*8];
      bf16x8 bfr1 = *(const bf16x8*)&w1b[(ot*16 + row)*WPAD + quad*8 + 32];
      const float bb = b1s[ot*16 + row];
      float sum_ = 0.f, sq_ = 0.f;
#pragma unroll
      for(int s = 0; s < 2; ++s){
        f32x4 acc = {0.f, 0.f, 0.f, 0.f};
        acc = __builtin_amdgcn_mfma_f32_16x16x32_bf16(afr[s][0], bfr0, acc, 0, 0, 0);
        acc = __builtin_amdgcn_mfma_f32_16x16x32_bf16(afr[s][1], bfr1, acc, 0, 0, 0);
#pragma unroll
        for(int r = 0; r < 4; ++r){
          float z = acc[r] + bb;
          sum_ += z; sq_ = fmaf(z, z, sq_);
        }
      }
      sum_ += __shfl_xor(sum_, 16, 64); sum_ += __shfl_xor(sum_, 32, 64);
      sq_  += __shfl_xor(sq_,  16, 64); sq_  += __shfl_xor(sq_,  32, 64);
      if(quad == 0){
        atomicAdd(&ssum[ot*16 + row], sum_);
        atomicAdd(&ssq [ot*16 + row], sq_);
      }
    }
  }
  __syncthreads();
  if(tid < 64)       atomicAdd(&gstats1[tid], ssum[tid]);
  else if(tid < 128) atomicAdd(&gstats1[tid], ssq[tid - 64]);
}

// ---------------------------------------------------------------------------
// 5) Layer 3 via MFMA, 512 m/block (r12). h2 staging wave-private; same mfma
//    order as layer2_stats; fused stats2 + k-group max/min. Transposed y1t.
// ---------------------------------------------------------------------------
__global__ __launch_bounds__(256)
void layer3_kernel(const uint16_t* __restrict__ y1t,
                   const float* __restrict__ gstats0,
                   const float* __restrict__ g0,
                   const float* __restrict__ bt0,
                   const float* __restrict__ w1,
                   const float* __restrict__ b1,
                   const float* __restrict__ gstats1,
                   const float* __restrict__ g1,
                   const float* __restrict__ bt1,
                   const float* __restrict__ w2,
                   const float* __restrict__ b2,
                   float* __restrict__ gstats2,
                   float* __restrict__ maxk,
                   float* __restrict__ mink){
  __shared__ short w1b[64*WPAD];
  __shared__ short w2b[128*WPAD];
  __shared__ short h2s[4][32*WPAD];
  __shared__ float la0s[64], lb0s[64], la1s[64], lb1s[64], b1s[64], b2s[128];
  __shared__ float ssum[128], ssq[128];
  const int tid = threadIdx.x;
#pragma unroll
  for(int i = 0; i < 16; ++i){
    int e = i*256 + tid;
    w1b[(e>>6)*WPAD + (e&63)] = (short)f2bf(w1[e]);
  }
#pragma unroll
  for(int i = 0; i < 32; ++i){
    int e = i*256 + tid;
    w2b[(e>>6)*WPAD + (e&63)] = (short)f2bf(w2[e]);
  }
  if(tid < 64){
    float mean = gstats0[tid] * (1.0f / M_);
    float var  = gstats0[64 + tid] * (1.0f / M_) - mean * mean;
    float inv  = 1.0f / sqrtf(var + EPS_);
    float a = g0[tid] * inv;
    la0s[tid] = a; lb0s[tid] = bt0[tid] - mean * a;
    b1s[tid] = b1[tid];
  } else if(tid < 128){
    int o = tid - 64;
    float mean = gstats1[o] * (1.0f / M_);
    float var  = gstats1[64 + o] * (1.0f / M_) - mean * mean;
    float inv  = 1.0f / sqrtf(var + EPS_);
    float a = g1[o] * inv;
    la1s[o] = a; lb1s[o] = bt1[o] - mean * a;
  }
  if(tid < 128){ b2s[tid] = b2[tid]; ssum[tid] = 0.f; }
  else         { ssq[tid - 128] = 0.f; }
  __syncthreads();

  const int wave = tid >> 6, lane = tid & 63;
  const int row = lane & 15, quad = lane >> 4;
  short* h2w = &h2s[wave][0];

  for(int ck = 0; ck < 4; ++ck){
    const int wm0 = blockIdx.x * 512 + ck * 128 + wave * 32;
    {
      bf16x8 afr[2][2];
#pragma unroll
      for(int s = 0; s < 2; ++s)
#pragma unroll
        for(int k2 = 0; k2 < 2; ++k2)
          afr[s][k2] = h1_frag(y1t, la0s, lb0s, wm0 + s*16 + row, quad*8 + k2*32);

      for(int ot = 0; ot < 4; ++ot){
        bf16x8 bfr0 = *(const bf16x8*)&w1b[(ot*16 + row)*WPAD + quad*8];
        bf16x8 bfr1 = *(const bf16x8*)&w1b[(ot*16 + row)*WPAD + quad*8 + 32];
        const int o = ot*16 + row;
        const float bb = b1s[o], a1 = la1s[o], c1 = lb1s[o];
#pragma unroll
        for(int s = 0; s < 2; ++s){
          f32x4 acc = {0.f, 0.f, 0.f, 0.f};
          acc = __builtin_amdgcn_mfma_f32_16x16x32_bf16(afr[s][0], bfr0, acc, 0, 0, 0);
          acc = __builtin_amdgcn_mfma_f32_16x16x32_bf16(afr[s][1], bfr1, acc, 0, 0, 0);
#pragma unroll
          for(int r = 0; r < 4; ++r){
            float z = acc[r] + bb;
            float h = fmaxf(a1 * z + c1, 0.0f);
            int ml = s*16 + quad*4 + r;
            h2w[ml*WPAD + o] = (short)f2bf(h);
          }
        }
      }
    }
    {
      bf16x8 hfr[2][2];
#pragma unroll
      for(int s = 0; s < 2; ++s)
#pragma unroll
        for(int k2 = 0; k2 < 2; ++k2)
          hfr[s][k2] = *(const bf16x8*)&h2w[(s*16 + row)*WPAD + quad*8 + k2*32];

      for(int ot = 0; ot < 8; ++ot){
        bf16x8 bfr0 = *(const bf16x8*)&w2b[(ot*16 + row)*WPAD + quad*8];
        bf16x8 bfr1 = *(const bf16x8*)&w2b[(ot*16 + row)*WPAD + quad*8 + 32];
        const int o = ot*16 + row;
        const float bb = b2s[o];
        float sum_ = 0.f, sq_ = 0.f, mx = -1e30f, mn = 1e30f;
#pragma unroll
        for(int s = 0; s < 2; ++s){
          f32x4 acc = {0.f, 0.f, 0.f, 0.f};
          acc = __builtin_amdgcn_mfma_f32_16x16x32_bf16(hfr[s][0], bfr0, acc, 0, 0, 0);
          acc = __builtin_amdgcn_mfma_f32_16x16x32_bf16(hfr[s][1], bfr1, acc, 0, 0, 0);
#pragma unroll
          for(int r = 0; r < 4; ++r){
            float z = acc[r] + bb;
            sum_ += z; sq_ = fmaf(z, z, sq_);
            mx = fmaxf(mx, z); mn = fminf(mn, z);
          }
        }
        sum_ += __shfl_xor(sum_, 16, 64); sum_ += __shfl_xor(sum_, 32, 64);
        sq_  += __shfl_xor(sq_,  16, 64); sq_  += __shfl_xor(sq_,  32, 64);
        mx = fmaxf(mx, __shfl_xor(mx, 16, 64)); mx = fmaxf(mx, __shfl_xor(mx, 32, 64));
        mn = fminf(mn, __shfl_xor(mn, 16, 64)); mn = fminf(mn, __shfl_xor(mn, 32, 64));
        if(quad == 0){
          atomicAdd(&ssum[o], sum_);
          atomicAdd(&ssq [o], sq_);
          maxk[(size_t)(wm0 >> 5) * 128 + o] = mx;
          mink[(size_t)(wm0 >> 5) * 128 + o] = mn;
        }
      }
    }
  }
  __syncthreads();
  if(tid < 128) atomicAdd(&gstats2[tid], ssum[tid]);
  else          atomicAdd(&gstats2[tid], ssq[tid - 128]);
}

// ---------------------------------------------------------------------------
// 6) Final: BN2+ReLU on max/min endpoints. Unchanged.
// ---------------------------------------------------------------------------
__global__ __launch_bounds__(256) void final_kernel(const float* __restrict__ maxk,
                                                    const float* __restrict__ mink,
                                                    const float* __restrict__ gstats2,
                                                    const float* __restrict__ g,
                                                    const float* __restrict__ bt,
                                                    float* __restrict__ out_np){
  const int gid = blockIdx.x * 256 + threadIdx.x;
  const int o = gid & 127;
  float mean = gstats2[o] * (1.0f / M_);
  float var  = gstats2[128 + o] * (1.0f / M_) - mean * mean;
  float inv  = 1.0f / sqrtf(var + EPS_);
  float a = g[o] * inv;
  float b = bt[o] - mean * a;
  float mx = maxk[gid], mn = mink[gid];
  out_np[gid] = fmaxf(fmaxf(a * mx + b, 0.0f), fmaxf(a * mn + b, 0.0f));
}

// ---------------------------------------------------------------------------
extern "C" void kernel_launch(void* const* d_in, const int* in_sizes, int n_in,
                              void* d_out, int out_size, void* d_ws, size_t ws_size,
                              hipStream_t stream){
  (void)in_sizes; (void)n_in; (void)out_size;
  const float* xyz = (const float*)d_in[0];
  const float* pts = (const float*)d_in[1];
  const float* w0 = (const float*)d_in[2];  const float* b0  = (const float*)d_in[3];
  const float* g0 = (const float*)d_in[4];  const float* bt0 = (const float*)d_in[5];
  const float* w1 = (const float*)d_in[6];  const float* b1  = (const float*)d_in[7];
  const float* g1 = (const float*)d_in[8];  const float* bt1 = (const float*)d_in[9];
  const float* w2 = (const float*)d_in[10]; const float* b2  = (const float*)d_in[11];
  const float* g2 = (const float*)d_in[12]; const float* bt2 = (const float*)d_in[13];

  float* out    = (float*)d_out;
  float* newxyz = out;                       // (B,S,3)
  float* newpts = out + (size_t)B_ * S_ * 3; // (B,S,128)

  const size_t off_gidx  = 0;
  const size_t off_stats = off_gidx  + (size_t)M_ * 4;
  const size_t off_maxk  = off_stats + 65536;
  const size_t off_mink  = off_maxk  + (size_t)NQ_ * 128 * 4;
  const size_t off_y1    = off_mink  + (size_t)NQ_ * 128 * 4;
  const size_t off_fd    = off_y1    + (size_t)M_ * 64 * 2;   // fps dist state
  const size_t off_ff    = off_fd    + (size_t)B_ * 8 * 256 * 8; // fps far
  const size_t need      = off_ff    + 256;
  if(ws_size < need) return;

  char* ws = (char*)d_ws;
  int*      gidx   = (int*)     (ws + off_gidx);
  float*    gstats = (float*)   (ws + off_stats);
  float*    maxk   = (float*)   (ws + off_maxk);
  float*    mink   = (float*)   (ws + off_mink);
  uint16_t* y1t    = (uint16_t*)(ws + off_y1);
  f32x2*    dstate = (f32x2*)   (ws + off_fd);
  int*      farws  = (int*)     (ws + off_ff);

  // L1: fps chunk 0 alone (nothing to overlap yet)
  fused_kernel<<<16, 256, 0, stream>>>(xyz, pts, newxyz, dstate, farws,
                                       gidx, gstats, w0, b0, y1t,
                                       16, 0*FCH, 1*FCH, 1, 0,
                                       0, 0, 0,   0);
  // L2: fps chunk 1 || ballq quarter 0 (zeros gstats)
  fused_kernel<<<16 + NBQ_, 256, 0, stream>>>(xyz, pts, newxyz, dstate, farws,
                                       gidx, gstats, w0, b0, y1t,
                                       16, 1*FCH, 2*FCH, 0, 0,
                                       NBQ_, 0, 1,   0);
  // L3: fps chunk 2 || ballq q1 || layer1 q0
  fused_kernel<<<16 + NBQ_ + NL1_, 256, 0, stream>>>(xyz, pts, newxyz, dstate, farws,
                                       gidx, gstats, w0, b0, y1t,
                                       16, 2*FCH, 3*FCH, 0, 0,
                                       NBQ_, 256, 0,   0);
  // L4: fps chunk 3 || ballq q2 || layer1 q1
  fused_kernel<<<16 + NBQ_ + NL1_, 256, 0, stream>>>(xyz, pts, newxyz, dstate, farws,
                                       gidx, gstats, w0, b0, y1t,
                                       16, 3*FCH, 4*FCH, 0, 1,
                                       NBQ_, 512, 0,   256);
  // L5: ballq q3 || layer1 q2
  fused_kernel<<<NBQ_ + NL1_, 256, 0, stream>>>(xyz, pts, newxyz, dstate, farws,
                                       gidx, gstats, w0, b0, y1t,
                                       0, 0, 0, 0, 0,
                                       NBQ_, 768, 0,   512);
  // L6: layer1 q3
  fused_kernel<<<NL1_, 256, 0, stream>>>(xyz, pts, newxyz, dstate, farws,
                                       gidx, gstats, w0, b0, y1t,
                                       0, 0, 0, 0, 0,
                                       0, 0, 0,   768);

  layer2_stats_kernel<<<M_ / 512, 256, 0, stream>>>(y1t, gstats, g0, bt0, w1, b1, gstats + 128);
  layer3_kernel      <<<M_ / 512, 256, 0, stream>>>(y1t, gstats, g0, bt0, w1, b1,
                                                    gstats + 128, g1, bt1, w2, b2,
                                                    gstats + 256, maxk, mink);
  final_kernel<<<(NQ_ * 128) / 256, 256, 0, stream>>>(maxk, mink, gstats + 256, g2, bt2, newpts);
}